// Round 1
// baseline (82.044 us; speedup 1.0000x reference)
//
#include <hip/hip_runtime.h>
#include <hip/hip_bf16.h>

// RoICrop: bilinear sampling with border clamp.
// input1: [R=128, C=512, H=37, W=37] f32
// input2: [R=128, 14, 14, 2] f32 in [-1,1], channel order (y, x)
// out:    [R, C, 14, 14] f32
//
// Strategy: block = (roi r, 4-channel chunk). Stage 4 contiguous planes
// (4*1369 floats = 21.9KB) in LDS with float4 coalesced loads; precompute
// the 196 grid points' corner offsets + lerp weights in LDS; emit 784
// contiguous output floats per block with coalesced writes.

#define RR 128
#define CC 512
#define HH 37
#define WW 37
#define GS 14
#define NP (GS * GS)        // 196
#define PLANE (HH * WW)     // 1369
#define CPB 4               // channels per block
#define NBLK (RR * (CC / CPB))  // 16384

__global__ __launch_bounds__(256) void roicrop_kernel(
    const float* __restrict__ feat,
    const float* __restrict__ grid,
    float* __restrict__ out)
{
    __shared__ float s_plane[CPB * PLANE];   // 21904 B, 16B aligned
    __shared__ float s_wy[NP];
    __shared__ float s_wx[NP];
    __shared__ int   s_o00[NP];
    __shared__ int   s_o01[NP];
    __shared__ int   s_o10[NP];
    __shared__ int   s_o11[NP];

    const int blk = blockIdx.x;
    const int r  = blk / (CC / CPB);
    const int cb = blk % (CC / CPB);
    const int c0 = cb * CPB;
    const int tid = threadIdx.x;

    // ---- grid coords -> corner offsets + weights (196 points) ----
    if (tid < NP) {
        const int p = tid;
        float gy = grid[((size_t)r * NP + p) * 2 + 0];
        float gx = grid[((size_t)r * NP + p) * 2 + 1];
        float y = (gy + 1.0f) * ((HH - 1) * 0.5f);
        float x = (gx + 1.0f) * ((WW - 1) * 0.5f);
        float y0f = floorf(y);
        float x0f = floorf(x);
        s_wy[p] = y - y0f;
        s_wx[p] = x - x0f;
        int y0 = (int)y0f;
        int x0 = (int)x0f;
        int y0i = min(max(y0,     0), HH - 1);
        int y1i = min(max(y0 + 1, 0), HH - 1);
        int x0i = min(max(x0,     0), WW - 1);
        int x1i = min(max(x0 + 1, 0), WW - 1);
        s_o00[p] = y0i * WW + x0i;
        s_o01[p] = y0i * WW + x1i;
        s_o10[p] = y1i * WW + x0i;
        s_o11[p] = y1i * WW + x1i;
    }

    // ---- stage 4 contiguous channel planes into LDS (float4) ----
    // byte offset of src = ((r*512 + c0)*1369)*4; (r*512+c0) % 4 == 0
    // -> float offset % 4 == 0 -> 16B aligned.
    const float* src = feat + ((size_t)r * CC + c0) * PLANE;
    const float4* src4 = reinterpret_cast<const float4*>(src);
    float4* s4 = reinterpret_cast<float4*>(s_plane);
    #pragma unroll
    for (int i = tid; i < (CPB * PLANE) / 4; i += 256) {  // 1369 float4s
        s4[i] = src4[i];
    }

    __syncthreads();

    // ---- compute 784 outputs, coalesced contiguous writes ----
    float* dst = out + ((size_t)r * CC + c0) * NP;
    #pragma unroll
    for (int o = tid; o < CPB * NP; o += 256) {
        const int cl = o / NP;
        const int p  = o - cl * NP;
        const float wy = s_wy[p];
        const float wx = s_wx[p];
        const float* pl = s_plane + cl * PLANE;
        float v00 = pl[s_o00[p]];
        float v01 = pl[s_o01[p]];
        float v10 = pl[s_o10[p]];
        float v11 = pl[s_o11[p]];
        float top = v00 + (v01 - v00) * wx;
        float bot = v10 + (v11 - v10) * wx;
        dst[o] = top + (bot - top) * wy;
    }
}

extern "C" void kernel_launch(void* const* d_in, const int* in_sizes, int n_in,
                              void* d_out, int out_size, void* d_ws, size_t ws_size,
                              hipStream_t stream) {
    const float* feat = (const float*)d_in[0];
    const float* grid = (const float*)d_in[1];
    float* out = (float*)d_out;
    roicrop_kernel<<<dim3(NBLK), dim3(256), 0, stream>>>(feat, grid, out);
}

// Round 2
// 80.779 us; speedup vs baseline: 1.0157x; 1.0157x over previous
//
#include <hip/hip_runtime.h>
#include <hip/hip_bf16.h>
#include <stdint.h>

// RoICrop: bilinear sampling with border clamp.
// input1: [R=128, C=512, H=37, W=37] f32
// input2: [R=128, 14, 14, 2] f32 in [-1,1], channel order (y, x)
// out:    [R, C, 14, 14] f32
//
// Block = (roi, 4-channel chunk). Stage 4 contiguous planes (21904 B) into
// LDS via async global_load_lds width-16 (issued FIRST, no VGPR round trip);
// grid-point math overlaps the in-flight DMA; compute emits 196 float4
// stores (4 consecutive points per thread).

#define RR 128
#define CC 512
#define HH 37
#define WW 37
#define GS 14
#define NP (GS * GS)            // 196
#define PLANE (HH * WW)         // 1369
#define CPB 4
#define NBLK (RR * (CC / CPB))  // 16384
#define PLANE_BYTES (CPB * PLANE * 4)              // 21904
#define NCHUNK ((PLANE_BYTES + 1023) / 1024)       // 22 (last = 400B -> 25 lanes)

typedef __attribute__((address_space(1))) const void gconst_void;
typedef __attribute__((address_space(3))) void lds_void;

__global__ __launch_bounds__(256) void roicrop_kernel(
    const float* __restrict__ feat,
    const float* __restrict__ grid,
    float* __restrict__ out)
{
    __shared__ float  s_plane[CPB * PLANE];  // 21904 B
    __shared__ float4 s_pt[NP];              // 3136 B: {wy, wx, pack(o00,o01), pack(o10,o11)}

    const int blk = blockIdx.x;
    const int r   = blk / (CC / CPB);
    const int cb  = blk % (CC / CPB);
    const int c0  = cb * CPB;
    const int tid  = threadIdx.x;
    const int wave = tid >> 6;
    const int lane = tid & 63;

    // ---- 1) issue async global->LDS staging (width 16) ----
    // src byte offset = (r*512+c0)*1369*4, c0%4==0 -> 16B aligned.
    const char* src = (const char*)(feat + ((size_t)r * CC + c0) * PLANE);
    char* lds_base = (char*)s_plane;
    #pragma unroll
    for (int ch = wave; ch < NCHUNK; ch += 4) {
        const int off = ch * 1024 + lane * 16;
        if (off + 16 <= PLANE_BYTES) {
            __builtin_amdgcn_global_load_lds(
                (gconst_void*)(src + off),
                (lds_void*)(lds_base + ch * 1024 + lane * 16),
                16, 0, 0);
        }
    }

    // ---- 2) grid coords -> packed point data (overlaps the DMA) ----
    if (tid < NP) {
        float2 g2 = reinterpret_cast<const float2*>(grid)[(size_t)r * NP + tid];
        float y = (g2.x + 1.0f) * 18.0f;   // (H-1)/2 == 18
        float x = (g2.y + 1.0f) * 18.0f;
        float y0f = floorf(y), x0f = floorf(x);
        float wy = y - y0f, wx = x - x0f;
        int y0 = (int)y0f, x0 = (int)x0f;
        int y0i = min(max(y0,     0), HH - 1);
        int y1i = min(max(y0 + 1, 0), HH - 1);
        int x0i = min(max(x0,     0), WW - 1);
        int x1i = min(max(x0 + 1, 0), WW - 1);
        uint32_t oa = (uint32_t)(y0i * WW + x0i) | ((uint32_t)(y0i * WW + x1i) << 16);
        uint32_t ob = (uint32_t)(y1i * WW + x0i) | ((uint32_t)(y1i * WW + x1i) << 16);
        s_pt[tid] = make_float4(wy, wx, __uint_as_float(oa), __uint_as_float(ob));
    }

    __syncthreads();   // drains vmcnt (global_load_lds) + lgkmcnt

    // ---- 3) compute: 196 float4 outputs (4 consecutive points, 1 channel) ----
    if (tid < NP) {
        const int cl = tid / 49;          // channel-local 0..3
        const int j  = tid - cl * 49;     // float4 index within plane, 0..48
        const int p0 = j * 4;
        const float* pl = s_plane + cl * PLANE;
        float4 o;
        float* op = &o.x;
        #pragma unroll
        for (int k = 0; k < 4; ++k) {
            float4 pt = s_pt[p0 + k];
            uint32_t oa = __float_as_uint(pt.z);
            uint32_t ob = __float_as_uint(pt.w);
            float v00 = pl[oa & 0xffffu];
            float v01 = pl[oa >> 16];
            float v10 = pl[ob & 0xffffu];
            float v11 = pl[ob >> 16];
            float top = v00 + (v01 - v00) * pt.y;
            float bot = v10 + (v11 - v10) * pt.y;
            op[k] = top + (bot - top) * pt.x;
        }
        // out float4 base: (r*512+c0)*196 floats, c0%4==0 -> 16B aligned.
        float4* dst = reinterpret_cast<float4*>(out + ((size_t)r * CC + c0) * NP);
        dst[tid] = o;
    }
}

extern "C" void kernel_launch(void* const* d_in, const int* in_sizes, int n_in,
                              void* d_out, int out_size, void* d_ws, size_t ws_size,
                              hipStream_t stream) {
    const float* feat = (const float*)d_in[0];
    const float* grid = (const float*)d_in[1];
    float* out = (float*)d_out;
    roicrop_kernel<<<dim3(NBLK), dim3(256), 0, stream>>>(feat, grid, out);
}